// Round 7
// baseline (684.718 us; speedup 1.0000x reference)
//
#include <hip/hip_runtime.h>
#include <hip/hip_bf16.h>

// AugmentedTripletLoss on MI355X.
// inputs [8192,128] f32, targets [8192] int, center [16,128] f32 -> scalar loss.
//
// v7: symmetry + max-TLP. dist(i,j)=dist(j,i): compute only upper-triangle
// 64x64 block-pairs (8256 blocks); each tile updates BOTH row-stats
// (v = sq_c - 2 dot) and col-stats (v' = v + sq_r - sq_c) -- min/max merges
// are idempotent so diagonal double-count is harmless. NO K-loop, NO
// prefetch: each wave loads its 22 fragments up front (one vmcnt drain),
// 16 MFMA, epilogue, global atomic merge. 32 blocks/CU of independent work
// lets the HW scheduler hide latency (v3/v5/v6 showed source-level pipelines
// regress). Stats arrays hold enc(extreme of sq_other - 2 dot) per element;
// row- and col-updates share the same arrays. Fused ticket finalize.

#define N_ROWS 8192
#define NPROTO 16
#define MARGIN_F 1.0f
#define EPS_F 1e-12f
#define NBLK_PD 8256  // 128*129/2 upper-triangle block pairs
#define ENC_PINF 0xFF800000u  // encf(+inf)
#define ENC_NINF 0x007FFFFFu  // encf(-inf)

typedef __attribute__((ext_vector_type(8))) short short8;   // 8 bf16 = 4 VGPRs
typedef __attribute__((ext_vector_type(4))) float float4v;  // MFMA acc

static __device__ __forceinline__ unsigned f2bf(float f) {
  unsigned u = __float_as_uint(f);
  u += 0x7fffu + ((u >> 16) & 1u);  // RNE
  return u >> 16;
}
// order-preserving float<->uint for atomicMin/Max
static __device__ __forceinline__ unsigned encf(float f) {
  unsigned u = __float_as_uint(f);
  return (u & 0x80000000u) ? ~u : (u | 0x80000000u);
}
static __device__ __forceinline__ float decf(unsigned e) {
  unsigned u = (e & 0x80000000u) ? (e ^ 0x80000000u) : ~e;
  return __uint_as_float(u);
}

// prep: row-major bf16 X (v2-proven layout: row*256 B, lane l owns dims
// l*8..l*8+7 as 16 B), sq, mindc, stat-array init, ticket init.
__global__ void prep_kernel(const float* __restrict__ x,
                            const float* __restrict__ center,
                            uint4* __restrict__ xbf4, float* __restrict__ sq,
                            float* __restrict__ mindc,
                            unsigned* __restrict__ pmaxU,
                            unsigned* __restrict__ pminU,
                            unsigned* __restrict__ counter) {
  __shared__ float scn[NPROTO * 128];  // raw centers, 8 KB
  __shared__ float sinv[NPROTO];       // 1/||center_p||
  int tid = threadIdx.x;
#pragma unroll
  for (int j = 0; j < 8; ++j) scn[j * 256 + tid] = center[j * 256 + tid];
  __syncthreads();
  int rloc = tid >> 4, l = tid & 15;
  {  // center norms (redundant per block; 2k FLOP)
    const float* c = &scn[rloc * 128 + l * 8];
    float ss = 0.f;
#pragma unroll
    for (int j = 0; j < 8; ++j) ss += c[j] * c[j];
#pragma unroll
    for (int m = 1; m < 16; m <<= 1) ss += __shfl_xor(ss, m, 64);
    if (l == 0) sinv[rloc] = 1.0f / sqrtf(ss);
  }
  __syncthreads();
  int row = blockIdx.x * 16 + rloc;
  float4 v0 = ((const float4*)x)[row * 32 + l * 2];
  float4 v1 = ((const float4*)x)[row * 32 + l * 2 + 1];
  float ss = v0.x * v0.x + v0.y * v0.y + v0.z * v0.z + v0.w * v0.w +
             v1.x * v1.x + v1.y * v1.y + v1.z * v1.z + v1.w * v1.w;
  float dots[NPROTO];
#pragma unroll
  for (int p = 0; p < NPROTO; ++p) {
    const float* c = &scn[p * 128 + l * 8];
    dots[p] = v0.x * c[0] + v0.y * c[1] + v0.z * c[2] + v0.w * c[3] +
              v1.x * c[4] + v1.y * c[5] + v1.z * c[6] + v1.w * c[7];
  }
#pragma unroll
  for (int m = 1; m < 16; m <<= 1) {
    ss += __shfl_xor(ss, m, 64);
#pragma unroll
    for (int p = 0; p < NPROTO; ++p) dots[p] += __shfl_xor(dots[p], m, 64);
  }
  uint4 pk;
  pk.x = f2bf(v0.x) | (f2bf(v0.y) << 16);
  pk.y = f2bf(v0.z) | (f2bf(v0.w) << 16);
  pk.z = f2bf(v1.x) | (f2bf(v1.y) << 16);
  pk.w = f2bf(v1.z) | (f2bf(v1.w) << 16);
  xbf4[row * 16 + l] = pk;  // row-major bf16, 256 B/row
  if (l == 0) {
    float mind2 = INFINITY;
#pragma unroll
    for (int p = 0; p < NPROTO; ++p)
      mind2 = fminf(mind2, ss + 1.0f - 2.0f * dots[p] * sinv[p]);
    sq[row] = ss;
    mindc[row] = fmaxf(sqrtf(fmaxf(mind2, 0.0f)), EPS_F);
  }
  // init stat arrays + ticket (stream-ordered before pairdist)
  if (tid < 16) pmaxU[blockIdx.x * 16 + tid] = ENC_NINF;       // max of v
  else if (tid < 32) pminU[blockIdx.x * 16 + tid - 16] = ENC_PINF;  // min of v
  if (blockIdx.x == 0 && tid == 32) *counter = 0u;
}

// 8256 blocks, one 64x64 row-group x col-group tile-pair each (j >= i).
// Wave w: rows i*64 + w*16 + [0,16), all 64 cols. No loops, no prefetch.
__global__ __launch_bounds__(256) void
pairdist_kernel(const char* __restrict__ xbf, const float* __restrict__ sq,
                const int* __restrict__ tgt, const float* __restrict__ mindc,
                unsigned* __restrict__ pmaxU, unsigned* __restrict__ pminU,
                unsigned* __restrict__ counter, float* __restrict__ out) {
  __shared__ float bsum[4];
  __shared__ int islast;
  int bid = blockIdx.x;
  // triangle decode: off(i) = 128i - i(i-1)/2; i = floor((257-sqrt(257^2-8b))/2)
  int i = (int)((257.0f - sqrtf((float)(66049 - 8 * bid))) * 0.5f);
  while ((i + 1) * 128 - ((i + 1) * i) / 2 <= bid) ++i;   // fixup (<=1 step)
  while (i * 128 - (i * (i - 1)) / 2 > bid) --i;
  int j = i + (bid - (i * 128 - (i * (i - 1)) / 2));

  int wave = threadIdx.x >> 6, lane = threadIdx.x & 63;
  int q = lane >> 4, l16 = lane & 15;
  int rowbase = i * 64 + wave * 16;
  int colbase = j * 64;

  // A frags (16 rows x K=128): A[m=l16][k=q*8+jj] (v2-proven row-major reads)
  short8 a[4];
  {
    const char* ar = xbf + (size_t)(rowbase + l16) * 256 + q * 16;
#pragma unroll
    for (int kc = 0; kc < 4; ++kc) a[kc] = *(const short8*)(ar + kc * 64);
  }
  // row metadata for rows rowbase + q*4 + r
  int4 tv = ((const int4*)tgt)[(rowbase >> 2) + q];
  int tr[4] = {tv.x, tv.y, tv.z, tv.w};
  float4 sv = ((const float4*)sq)[(rowbase >> 2) + q];
  float sqr[4] = {sv.x, sv.y, sv.z, sv.w};

  // B frags for the 4 col tiles + col metadata
  short8 b[4][4];
  float sqc[4];
  int tgc[4];
#pragma unroll
  for (int tt = 0; tt < 4; ++tt) {
    const char* br = xbf + (size_t)(colbase + tt * 16 + l16) * 256 + q * 16;
#pragma unroll
    for (int kc = 0; kc < 4; ++kc) b[tt][kc] = *(const short8*)(br + kc * 64);
    sqc[tt] = sq[colbase + tt * 16 + l16];
    tgc[tt] = tgt[colbase + tt * 16 + l16];
  }

  float4v acc[4];
#pragma unroll
  for (int tt = 0; tt < 4; ++tt) acc[tt] = (float4v){0.f, 0.f, 0.f, 0.f};
#pragma unroll
  for (int kc = 0; kc < 4; ++kc)
#pragma unroll
    for (int tt = 0; tt < 4; ++tt)  // 4 independent acc chains
      acc[tt] = __builtin_amdgcn_mfma_f32_16x16x32_bf16(a[kc], b[tt][kc],
                                                        acc[tt], 0, 0, 0);

  // epilogue. v = sq_c - 2 dot (row view: dist2 = sq_r + v);
  // v' = v + sq_r - sq_c (col view: dist2 = sq_c + v').
  float rp[4], rn[4], cp[4], cn[4];
#pragma unroll
  for (int r = 0; r < 4; ++r) { rp[r] = -INFINITY; rn[r] = INFINITY; }
#pragma unroll
  for (int tt = 0; tt < 4; ++tt) { cp[tt] = -INFINITY; cn[tt] = INFINITY; }
#pragma unroll
  for (int tt = 0; tt < 4; ++tt) {
#pragma unroll
    for (int r = 0; r < 4; ++r) {
      float v = fmaf(-2.0f, acc[tt][r], sqc[tt]);
      bool same = (tgc[tt] == tr[r]);
      rp[r] = fmaxf(rp[r], same ? v : -INFINITY);   // farthest same (row)
      rn[r] = fminf(rn[r], same ? INFINITY : v);    // nearest diff (row)
      float vp = v + (sqr[r] - sqc[tt]);
      cp[tt] = fmaxf(cp[tt], same ? vp : -INFINITY);  // farthest same (col)
      cn[tt] = fminf(cn[tt], same ? INFINITY : vp);   // nearest diff (col)
    }
  }
  // row stats: reduce over the 16 cols held across l16 lanes
#pragma unroll
  for (int m = 1; m < 16; m <<= 1) {
#pragma unroll
    for (int r = 0; r < 4; ++r) {
      rp[r] = fmaxf(rp[r], __shfl_xor(rp[r], m, 64));
      rn[r] = fminf(rn[r], __shfl_xor(rn[r], m, 64));
    }
  }
  if (l16 == 0) {
#pragma unroll
    for (int r = 0; r < 4; ++r) {
      atomicMax(&pmaxU[rowbase + q * 4 + r], encf(rp[r]));
      atomicMin(&pminU[rowbase + q * 4 + r], encf(rn[r]));
    }
  }
  // col stats: reduce over the 16 rows held across q lanes
#pragma unroll
  for (int m = 16; m < 64; m <<= 1) {
#pragma unroll
    for (int tt = 0; tt < 4; ++tt) {
      cp[tt] = fmaxf(cp[tt], __shfl_xor(cp[tt], m, 64));
      cn[tt] = fminf(cn[tt], __shfl_xor(cn[tt], m, 64));
    }
  }
  if (q == 0) {
#pragma unroll
    for (int tt = 0; tt < 4; ++tt) {
      atomicMax(&pmaxU[colbase + tt * 16 + l16], encf(cp[tt]));
      atomicMin(&pminU[colbase + tt * 16 + l16], encf(cn[tt]));
    }
  }

  __threadfence();  // release our atomics
  __syncthreads();
  if (threadIdx.x == 0) islast = (atomicAdd(counter, 1u) == NBLK_PD - 1u);
  __syncthreads();
  if (!islast) return;
  __threadfence();  // acquire: all blocks' atomics visible
  float lsum = 0.f;
#pragma unroll 4
  for (int k = 0; k < N_ROWS / 256; ++k) {
    int idx = k * 256 + threadIdx.x;
    unsigned ep = __hip_atomic_load(&pmaxU[idx], __ATOMIC_RELAXED,
                                    __HIP_MEMORY_SCOPE_AGENT);
    unsigned en = __hip_atomic_load(&pminU[idx], __ATOMIC_RELAXED,
                                    __HIP_MEMORY_SCOPE_AGENT);
    float si = sq[idx];
    float dap = sqrtf(fmaxf(si + decf(ep), EPS_F));
    float dan = (en == ENC_PINF) ? (dap + MARGIN_F)
                                 : sqrtf(fmaxf(si + decf(en), EPS_F));
    dan = fminf(dan, mindc[idx]);
    lsum += fmaxf(dap - dan + MARGIN_F, 0.0f);
  }
#pragma unroll
  for (int m = 1; m < 64; m <<= 1) lsum += __shfl_xor(lsum, m, 64);
  if (lane == 0) bsum[wave] = lsum;
  __syncthreads();
  if (threadIdx.x == 0)
    out[0] = (bsum[0] + bsum[1] + bsum[2] + bsum[3]) * (1.0f / (float)N_ROWS);
}

extern "C" void kernel_launch(void* const* d_in, const int* in_sizes, int n_in,
                              void* d_out, int out_size, void* d_ws, size_t ws_size,
                              hipStream_t stream) {
  const float* inputs = (const float*)d_in[0];
  const int* targets = (const int*)d_in[1];
  const float* center = (const float*)d_in[2];
  char* ws = (char*)d_ws;
  uint4* xbf4       = (uint4*)(ws + 0);            // 2 MB row-major bf16 X
  float* sq         = (float*)(ws + 2097152);      // 32 KB
  float* mindc      = (float*)(ws + 2129920);      // 32 KB
  unsigned* pmaxU   = (unsigned*)(ws + 2162688);   // 32 KB enc(max of sq_o-2dot)
  unsigned* pminU   = (unsigned*)(ws + 2195456);   // 32 KB enc(min of sq_o-2dot)
  unsigned* counter = (unsigned*)(ws + 2228224);   // 4 B ticket
  float* out        = (float*)d_out;

  prep_kernel<<<512, 256, 0, stream>>>(inputs, center, xbf4, sq, mindc,
                                       pmaxU, pminU, counter);
  pairdist_kernel<<<NBLK_PD, 256, 0, stream>>>((const char*)xbf4, sq, targets,
                                               mindc, pmaxU, pminU, counter, out);
}